// Round 1
// baseline (216.280 us; speedup 1.0000x reference)
//
#include <hip/hip_runtime.h>

// TransR scoring: out[b] = -sum_j | (h_head[b]-h_tail[b]) . P_r[:,j] + e_r[j] |
// B=32768, NFEATS=128, RFEATS=64, NUM_RELS=1000
//
// One wave (64 lanes) per row b.
//   lane = jg + 16*part;  jg in [0,16): owns 4 output columns (jg*4..jg*4+3)
//                         part in [0,4): owns 32 contiguous n-rows of P
// Per k-step: 4x global float4 loads of P rows (coalesced 256B segments),
// 1x broadcast ds_read_b128 of d (padded LDS, conflict-free), 16 FMAs.

#define NFEATS 128
#define RFEATS 64

__global__ __launch_bounds__(256, 4) void transr_kernel(
    const float* __restrict__ h_head,
    const float* __restrict__ h_tail,
    const int*   __restrict__ rels,
    const float* __restrict__ rel_emb,
    const float* __restrict__ rel_proj,
    float* __restrict__ out)
{
    const int wave = threadIdx.x >> 6;
    const int lane = threadIdx.x & 63;
    const int b    = blockIdx.x * 4 + wave;

    const int jg   = lane & 15;   // column group (4 columns)
    const int part = lane >> 4;   // n-partition (32 contiguous rows of P)

    // padded d storage: word index for n is (n>>5)*36 + (n&31)
    // -> part p's 32 words start at bank 4p, conflict-free b128 broadcast reads
    __shared__ float d_lds[4][4 * 36];

    // d = h_head - h_tail (two coalesced 256B loads per wave)
    const float* hh = h_head + (size_t)b * NFEATS;
    const float* ht = h_tail + (size_t)b * NFEATS;
    {
        float d0 = hh[lane]      - ht[lane];
        float d1 = hh[64 + lane] - ht[64 + lane];
        d_lds[wave][((lane)      >> 5) * 36 + (lane & 31)] = d0;
        d_lds[wave][((64 + lane) >> 5) * 36 + (lane & 31)] = d1;
    }
    __syncthreads();  // cheap; guarantees LDS writes visible before reads

    const int r = rels[b];
    const float* pr = rel_proj + (size_t)r * (NFEATS * RFEATS)
                               + (size_t)(part * 32) * RFEATS + jg * 4;
    const float* dl = &d_lds[wave][part * 36];

    float acc0 = 0.f, acc1 = 0.f, acc2 = 0.f, acc3 = 0.f;

#pragma unroll
    for (int kk = 0; kk < 8; ++kk) {
        float4 d4 = *(const float4*)(dl + kk * 4);
        float4 p0 = *(const float4*)(pr + (size_t)(kk * 4 + 0) * RFEATS);
        float4 p1 = *(const float4*)(pr + (size_t)(kk * 4 + 1) * RFEATS);
        float4 p2 = *(const float4*)(pr + (size_t)(kk * 4 + 2) * RFEATS);
        float4 p3 = *(const float4*)(pr + (size_t)(kk * 4 + 3) * RFEATS);

        acc0 = fmaf(d4.x, p0.x, acc0);
        acc1 = fmaf(d4.x, p0.y, acc1);
        acc2 = fmaf(d4.x, p0.z, acc2);
        acc3 = fmaf(d4.x, p0.w, acc3);

        acc0 = fmaf(d4.y, p1.x, acc0);
        acc1 = fmaf(d4.y, p1.y, acc1);
        acc2 = fmaf(d4.y, p1.z, acc2);
        acc3 = fmaf(d4.y, p1.w, acc3);

        acc0 = fmaf(d4.z, p2.x, acc0);
        acc1 = fmaf(d4.z, p2.y, acc1);
        acc2 = fmaf(d4.z, p2.z, acc2);
        acc3 = fmaf(d4.z, p2.w, acc3);

        acc0 = fmaf(d4.w, p3.x, acc0);
        acc1 = fmaf(d4.w, p3.y, acc1);
        acc2 = fmaf(d4.w, p3.z, acc2);
        acc3 = fmaf(d4.w, p3.w, acc3);
    }

    // reduce over the 4 n-partitions (lanes jg, jg+16, jg+32, jg+48)
    acc0 += __shfl_xor(acc0, 16); acc0 += __shfl_xor(acc0, 32);
    acc1 += __shfl_xor(acc1, 16); acc1 += __shfl_xor(acc1, 32);
    acc2 += __shfl_xor(acc2, 16); acc2 += __shfl_xor(acc2, 32);
    acc3 += __shfl_xor(acc3, 16); acc3 += __shfl_xor(acc3, 32);

    // add relation embedding, abs, per-lane partial L1
    float4 e = *(const float4*)(rel_emb + (size_t)r * RFEATS + jg * 4);
    float s = fabsf(acc0 + e.x) + fabsf(acc1 + e.y)
            + fabsf(acc2 + e.z) + fabsf(acc3 + e.w);

    // reduce over the 16 column groups
    s += __shfl_xor(s, 1);
    s += __shfl_xor(s, 2);
    s += __shfl_xor(s, 4);
    s += __shfl_xor(s, 8);

    if (lane == 0) out[b] = -s;
}

extern "C" void kernel_launch(void* const* d_in, const int* in_sizes, int n_in,
                              void* d_out, int out_size, void* d_ws, size_t ws_size,
                              hipStream_t stream) {
    const float* h_head   = (const float*)d_in[0];
    const float* h_tail   = (const float*)d_in[1];
    const int*   rels     = (const int*)d_in[2];   // jax default x64-disabled -> int32
    const float* rel_emb  = (const float*)d_in[3];
    const float* rel_proj = (const float*)d_in[4];
    float* out = (float*)d_out;

    const int B = in_sizes[2];            // 32768 rows
    const int blocks = B / 4;             // 4 waves per block, 1 row per wave

    transr_kernel<<<blocks, 256, 0, stream>>>(h_head, h_tail, rels, rel_emb,
                                              rel_proj, out);
}

// Round 2
// 134.841 us; speedup vs baseline: 1.6040x; 1.6040x over previous
//
#include <hip/hip_runtime.h>

// TransR scoring, bucketed-by-relation formulation.
//   out[b] = -sum_j | (h_head[b]-h_tail[b]) . P_r[:,j] + e_r[j] |
// B=32768, NFEATS=128, RFEATS=64, NUM_RELS=1000.
//
// Round-1 counters: FETCH_SIZE=481 MB (L2 thrash on random 32KB matrix
// gathers), 3.67 TB/s, 134 us. Fix: counting-sort rows by relation, then
// one block per relation stages P_r in LDS once and streams its ~33 rows.
// Logical P traffic: 1 GB -> 32 MB. Total HBM ~70 MB -> ~11 us floor.
//
// Pipeline (all on `stream`, graph-capture safe, ws re-zeroed every call):
//   K0 zero counts+cursors -> K1 histogram -> K2 scan (1 block) ->
//   K3 atomic scatter (order within bucket irrelevant) -> K4 main.

#define NFEATS   128
#define RFEATS   64
#define NUM_RELS 1000

__global__ void zero_kernel(int* __restrict__ p, int n) {
    int i = blockIdx.x * blockDim.x + threadIdx.x;
    if (i < n) p[i] = 0;
}

__global__ void hist_kernel(const int* __restrict__ rels,
                            int* __restrict__ counts, int B) {
    int i = blockIdx.x * blockDim.x + threadIdx.x;
    if (i < B) atomicAdd(&counts[rels[i]], 1);
}

__global__ void scan_kernel(const int* __restrict__ counts,
                            int* __restrict__ offsets) {
    __shared__ int buf[1024];
    const int t = threadIdx.x;
    const int c = (t < NUM_RELS) ? counts[t] : 0;
    buf[t] = c;
    __syncthreads();
    for (int off = 1; off < 1024; off <<= 1) {
        int v = (t >= off) ? buf[t - off] : 0;
        __syncthreads();
        buf[t] += v;
        __syncthreads();
    }
    if (t < NUM_RELS) offsets[t] = buf[t] - c;   // exclusive prefix
}

__global__ void scatter_kernel(const int* __restrict__ rels,
                               const int* __restrict__ offsets,
                               int* __restrict__ cursors,
                               int* __restrict__ bucket, int B) {
    int i = blockIdx.x * blockDim.x + threadIdx.x;
    if (i < B) {
        int r = rels[i];
        int slot = offsets[r] + atomicAdd(&cursors[r], 1);
        bucket[slot] = i;
    }
}

// One block (256 thr = 4 waves) per relation. LDS: P 32KB + d-tile 8KB = 40KB
// -> 4 blocks/CU (160KB), 16 waves/CU.
// Wave processes 4 rows/chunk. lane = jg + 16*np: jg owns cols 4jg..4jg+3,
// np owns n in [32np, 32np+32). Same accumulation topology as round-1 kernel
// (validated absmax=0.0).
__global__ __launch_bounds__(256, 4) void transr_main(
    const float* __restrict__ h_head,
    const float* __restrict__ h_tail,
    const float* __restrict__ rel_emb,
    const float* __restrict__ rel_proj,
    const int*   __restrict__ offsets,
    const int*   __restrict__ counts,
    const int*   __restrict__ bucket,
    float* __restrict__ out)
{
    __shared__ float Plds[NFEATS * RFEATS];   // 32 KB, row-major [n][j]
    __shared__ float Dlds[4][4][NFEATS];      // 8 KB: [wave][row][n]

    const int r     = blockIdx.x;
    const int cnt   = counts[r];
    const int start = offsets[r];
    if (cnt == 0) return;                     // uniform exit, before barriers

    const int tid  = threadIdx.x;
    const int w    = tid >> 6;
    const int lane = tid & 63;
    const int jg   = lane & 15;
    const int np   = lane >> 4;

    // stage P_r: 8192 floats, 8 rounds of 256 x float4 (coalesced)
    {
        const float4* src = (const float4*)(rel_proj + (size_t)r * (NFEATS * RFEATS));
        float4* dst = (float4*)Plds;
#pragma unroll
        for (int it = 0; it < 8; ++it)
            dst[it * 256 + tid] = src[it * 256 + tid];
    }
    __syncthreads();

    const float4 e = *(const float4*)(rel_emb + (size_t)r * RFEATS + jg * 4);
    float* Dw = &Dlds[w][0][0];

    for (int base = 0; base < cnt; base += 16) {
        // ---- stage d = h_head - h_tail for this wave's 4 rows (per-wave LDS
        // region; same-wave ds ordering, no barrier needed) ----
        int rowids[4];
#pragma unroll
        for (int rr = 0; rr < 4; ++rr) {
            const int li = base + w * 4 + rr;
            rowids[rr] = (li < cnt) ? bucket[start + li] : -1;
            if (rowids[rr] >= 0) {
                const float2 a = *(const float2*)(h_head + (size_t)rowids[rr] * NFEATS + lane * 2);
                const float2 b = *(const float2*)(h_tail + (size_t)rowids[rr] * NFEATS + lane * 2);
                float2 d; d.x = a.x - b.x; d.y = a.y - b.y;
                *(float2*)(Dw + rr * NFEATS + lane * 2) = d;
            }
        }

        // ---- 4-row x 64-col GEMV slice from LDS ----
        float acc[4][4] = {{0.f}};
#pragma unroll 4
        for (int k = 0; k < 32; ++k) {
            const int n = np * 32 + k;
            const float4 p = *(const float4*)&Plds[n * RFEATS + jg * 4];
#pragma unroll
            for (int rr = 0; rr < 4; ++rr) {
                const float dv = Dw[rr * NFEATS + n];
                acc[rr][0] = fmaf(dv, p.x, acc[rr][0]);
                acc[rr][1] = fmaf(dv, p.y, acc[rr][1]);
                acc[rr][2] = fmaf(dv, p.z, acc[rr][2]);
                acc[rr][3] = fmaf(dv, p.w, acc[rr][3]);
            }
        }

        // ---- reduce over np (xor 16,32), then cols, then jg (xor 1,2,4,8) ----
        float s[4];
#pragma unroll
        for (int rr = 0; rr < 4; ++rr) {
#pragma unroll
            for (int c = 0; c < 4; ++c) {
                acc[rr][c] += __shfl_xor(acc[rr][c], 16);
                acc[rr][c] += __shfl_xor(acc[rr][c], 32);
            }
            float sv = fabsf(acc[rr][0] + e.x) + fabsf(acc[rr][1] + e.y)
                     + fabsf(acc[rr][2] + e.z) + fabsf(acc[rr][3] + e.w);
            sv += __shfl_xor(sv, 1);
            sv += __shfl_xor(sv, 2);
            sv += __shfl_xor(sv, 4);
            sv += __shfl_xor(sv, 8);
            s[rr] = sv;
        }
        if (lane == 0) {
#pragma unroll
            for (int rr = 0; rr < 4; ++rr)
                if (rowids[rr] >= 0) out[rowids[rr]] = -s[rr];
        }
    }
}

extern "C" void kernel_launch(void* const* d_in, const int* in_sizes, int n_in,
                              void* d_out, int out_size, void* d_ws, size_t ws_size,
                              hipStream_t stream) {
    const float* h_head   = (const float*)d_in[0];
    const float* h_tail   = (const float*)d_in[1];
    const int*   rels     = (const int*)d_in[2];   // int32 on device (x64 off)
    const float* rel_emb  = (const float*)d_in[3];
    const float* rel_proj = (const float*)d_in[4];
    float* out = (float*)d_out;

    const int B = in_sizes[2];   // 32768

    // workspace layout (ints): counts[1024] | cursors[1024] | offsets[1024] | bucket[B]
    int* counts  = (int*)d_ws;
    int* cursors = counts + 1024;
    int* offsets = cursors + 1024;
    int* bucket  = offsets + 1024;

    zero_kernel<<<8, 256, 0, stream>>>(counts, 2048);  // counts + cursors
    hist_kernel<<<(B + 255) / 256, 256, 0, stream>>>(rels, counts, B);
    scan_kernel<<<1, 1024, 0, stream>>>(counts, offsets);
    scatter_kernel<<<(B + 255) / 256, 256, 0, stream>>>(rels, offsets, cursors, bucket, B);
    transr_main<<<NUM_RELS, 256, 0, stream>>>(h_head, h_tail, rel_emb, rel_proj,
                                              offsets, counts, bucket, out);
}